// Round 3
// baseline (629.576 us; speedup 1.0000x reference)
//
#include <hip/hip_runtime.h>

#define NFEAT 256
#define DHEAD 64
#define NSEQ  4096
#define NHEADS 32

constexpr float NORM_C  = 0.35355339059327373f;  // 64^-0.25
constexpr float RATIO_C = 0.0625f;               // 256^-0.5
constexpr float DIAG_C  = 0.0625f;               // 0.5 * 64^-0.5
constexpr float KEPS_C  = 1e-4f;

using v8s = __attribute__((ext_vector_type(8))) short;
using v4f = __attribute__((ext_vector_type(4))) float;
union Frag8 { v8s v; ushort u[8]; };

__device__ __forceinline__ ushort bf16h(float x) {
  unsigned u = __float_as_uint(x);
  return (ushort)((u + 0x7FFFu + ((u >> 16) & 1)) >> 16);
}
__device__ __forceinline__ float bf16f(ushort h) {
  return __uint_as_float(((unsigned)h) << 16);
}
__device__ __forceinline__ unsigned enc_f(float f) {
  unsigned u = __float_as_uint(f);
  return (u & 0x80000000u) ? ~u : (u | 0x80000000u);
}
__device__ __forceinline__ float dec_f(unsigned e) {
  return (e & 0x80000000u) ? __uint_as_float(e ^ 0x80000000u) : __uint_as_float(~e);
}

#define MFMA(a, b, c) __builtin_amdgcn_mfma_f32_16x16x32_bf16((a), (b), (c), 0, 0, 0)

// split P (with NORM folded) into bf16 hi/lo planes, layout [j][d]
__global__ void prep_kernel(const float* __restrict__ proj,
                            ushort* __restrict__ Phi, ushort* __restrict__ Plo) {
  int i = blockIdx.x * 256 + threadIdx.x;
  if (i < NFEAT * DHEAD) {
    float x = NORM_C * proj[i];
    ushort h = bf16h(x);
    Phi[i] = h;
    Plo[i] = bf16h(x - bf16f(h));
  }
}

// ---------------------------------------------------------------------------
// kmax: global max of dd_k via MFMA. 1024 blocks: head = bid>>5, slab = bid&31
// (128 rows, 4 chunks of 32). A prefetched one chunk ahead.
// ---------------------------------------------------------------------------
__global__ __launch_bounds__(256, 3) void kmax_kernel(
    const float* __restrict__ kk, const ushort* __restrict__ Phi,
    const ushort* __restrict__ Plo, unsigned* __restrict__ kmax_u) {
  __shared__ float wred[4];
  const int t = threadIdx.x, lane = t & 63, w = t >> 6;
  const int cl = lane & 15, q = lane >> 4;
  const int mw = w & 1, jw = w >> 1;
  const int head = blockIdx.x >> 5, slab = blockIdx.x & 31;
  const float* abase =
      kk + ((size_t)(head * NSEQ + slab * 128 + mw * 16 + cl)) * DHEAD + q * 8;
  float4 pa0 = *(const float4*)(abase);
  float4 pa1 = *(const float4*)(abase + 4);
  float4 pa2 = *(const float4*)(abase + 32);
  float4 pa3 = *(const float4*)(abase + 36);
  float mx = -3.0e38f;
  for (int c = 0; c < 4; ++c) {
    float af[2][8] = {{pa0.x, pa0.y, pa0.z, pa0.w, pa1.x, pa1.y, pa1.z, pa1.w},
                      {pa2.x, pa2.y, pa2.z, pa2.w, pa3.x, pa3.y, pa3.z, pa3.w}};
    Frag8 ah[2], al[2];
#pragma unroll
    for (int ks = 0; ks < 2; ++ks)
#pragma unroll
      for (int i = 0; i < 8; ++i) {
        ushort h = bf16h(af[ks][i]);
        ah[ks].u[i] = h;
        al[ks].u[i] = bf16h(af[ks][i] - bf16f(h));
      }
    if (c < 3) {  // prefetch next chunk
      const float* nx = abase + (size_t)(c + 1) * 32 * DHEAD;
      pa0 = *(const float4*)(nx);
      pa1 = *(const float4*)(nx + 4);
      pa2 = *(const float4*)(nx + 32);
      pa3 = *(const float4*)(nx + 36);
    }
    v4f acc[8];
#pragma unroll
    for (int jt = 0; jt < 8; ++jt) acc[jt] = (v4f){0.f, 0.f, 0.f, 0.f};
#pragma unroll
    for (int ks = 0; ks < 2; ++ks)
#pragma unroll
      for (int jt = 0; jt < 8; ++jt) {
        int j = jw * 128 + jt * 16 + cl;
        v8s bh = *(const v8s*)(Phi + j * 64 + ks * 32 + q * 8);
        v8s bl = *(const v8s*)(Plo + j * 64 + ks * 32 + q * 8);
        acc[jt] = MFMA(ah[ks].v, bh, acc[jt]);
        acc[jt] = MFMA(ah[ks].v, bl, acc[jt]);
        acc[jt] = MFMA(al[ks].v, bh, acc[jt]);
      }
#pragma unroll
    for (int jt = 0; jt < 8; ++jt)
#pragma unroll
      for (int r = 0; r < 4; ++r) mx = fmaxf(mx, acc[jt][r]);
  }
  for (int s = 1; s < 64; s <<= 1) mx = fmaxf(mx, __shfl_xor(mx, s));
  if (lane == 0) wred[w] = mx;
  __syncthreads();
  if (t == 0)
    atomicMax(kmax_u,
              enc_f(fmaxf(fmaxf(wred[0], wred[1]), fmaxf(wred[2], wred[3]))));
}

// ---------------------------------------------------------------------------
// kctx: dd_k -> kp (exp) -> LDS -> ctx += kp^T * v, ksum += kp.
// 1024 blocks, XCD-swizzled (head&7 == bid&7). A/V prefetched a chunk ahead.
// ---------------------------------------------------------------------------
#define KPS 40
__global__ __launch_bounds__(256, 3) void kctx_kernel(
    const float* __restrict__ kk, const float* __restrict__ vv,
    const ushort* __restrict__ Phi, const ushort* __restrict__ Plo,
    const unsigned* __restrict__ kmax_u, float* __restrict__ ksum,
    float* __restrict__ ctx) {
  __shared__ __align__(16) ushort kphi[NFEAT * KPS];  // 20 KB  [j][n]
  __shared__ __align__(16) ushort kplo[NFEAT * KPS];  // 20 KB
  __shared__ __align__(16) ushort vthi[DHEAD * KPS];  // 5 KB   [e][n]
  __shared__ __align__(16) ushort vtlo[DHEAD * KPS];  // 5 KB
  __shared__ float diag[32];
  const int t = threadIdx.x, lane = t & 63, w = t >> 6;
  const int cl = lane & 15, q = lane >> 4;
  const int mw = w & 1, jw = w >> 1;
  const int xcd = blockIdx.x & 7, bi = blockIdx.x >> 3;
  const int head = ((bi >> 5) << 3) | xcd, slab = bi & 31;
  const float m = dec_f(*kmax_u);
  float ksacc[8] = {0.f, 0.f, 0.f, 0.f, 0.f, 0.f, 0.f, 0.f};
  v4f ctxacc[4][4];
#pragma unroll
  for (int jj = 0; jj < 4; ++jj)
#pragma unroll
    for (int et = 0; et < 4; ++et) ctxacc[jj][et] = (v4f){0.f, 0.f, 0.f, 0.f};

  const float* abase =
      kk + ((size_t)(head * NSEQ + slab * 128 + mw * 16 + cl)) * DHEAD + q * 8;
  const int np = t >> 4, e0 = (t & 15) * 4;
  const float* vbase =
      vv + ((size_t)(head * NSEQ + slab * 128 + np * 2)) * DHEAD + e0;
  float4 pa0 = *(const float4*)(abase);
  float4 pa1 = *(const float4*)(abase + 4);
  float4 pa2 = *(const float4*)(abase + 32);
  float4 pa3 = *(const float4*)(abase + 36);
  float4 pv0 = *(const float4*)(vbase);
  float4 pv1 = *(const float4*)(vbase + DHEAD);

  for (int c = 0; c < 4; ++c) {
    __syncthreads();  // kp/vt free (prev phase3 done)
    // stage v^T (bf16 hi/lo), layout [e][n], from prefetched regs
    {
      float fa[4] = {pv0.x, pv0.y, pv0.z, pv0.w};
      float fb[4] = {pv1.x, pv1.y, pv1.z, pv1.w};
#pragma unroll
      for (int cc = 0; cc < 4; ++cc) {
        int e = e0 + cc;
        ushort h0 = bf16h(fa[cc]), h1 = bf16h(fb[cc]);
        ushort l0 = bf16h(fa[cc] - bf16f(h0)), l1 = bf16h(fb[cc] - bf16f(h1));
        *(uint*)&vthi[e * KPS + np * 2] = (uint)h0 | ((uint)h1 << 16);
        *(uint*)&vtlo[e * KPS + np * 2] = (uint)l0 | ((uint)l1 << 16);
      }
    }
    // A split from prefetched regs
    float af[2][8] = {{pa0.x, pa0.y, pa0.z, pa0.w, pa1.x, pa1.y, pa1.z, pa1.w},
                      {pa2.x, pa2.y, pa2.z, pa2.w, pa3.x, pa3.y, pa3.z, pa3.w}};
    Frag8 ah[2], al[2];
    float ssq = 0.f;
#pragma unroll
    for (int ks = 0; ks < 2; ++ks)
#pragma unroll
      for (int i = 0; i < 8; ++i) {
        float x = af[ks][i];
        ssq = fmaf(x, x, ssq);
        ushort h = bf16h(x);
        ah[ks].u[i] = h;
        al[ks].u[i] = bf16h(x - bf16f(h));
      }
    if (c < 3) {  // prefetch next chunk (hides HBM latency under phases 1-3)
      const float* nx = abase + (size_t)(c + 1) * 32 * DHEAD;
      pa0 = *(const float4*)(nx);
      pa1 = *(const float4*)(nx + 4);
      pa2 = *(const float4*)(nx + 32);
      pa3 = *(const float4*)(nx + 36);
      const float* nv = vbase + (size_t)(c + 1) * 32 * DHEAD;
      pv0 = *(const float4*)(nv);
      pv1 = *(const float4*)(nv + DHEAD);
    }
    // phase 1: dd_k tile via MFMA
    v4f acc[8];
#pragma unroll
    for (int jt = 0; jt < 8; ++jt) acc[jt] = (v4f){0.f, 0.f, 0.f, 0.f};
#pragma unroll
    for (int ks = 0; ks < 2; ++ks)
#pragma unroll
      for (int jt = 0; jt < 8; ++jt) {
        int j = jw * 128 + jt * 16 + cl;
        v8s bh = *(const v8s*)(Phi + j * 64 + ks * 32 + q * 8);
        v8s bl = *(const v8s*)(Plo + j * 64 + ks * 32 + q * 8);
        acc[jt] = MFMA(ah[ks].v, bh, acc[jt]);
        acc[jt] = MFMA(ah[ks].v, bl, acc[jt]);
        acc[jt] = MFMA(al[ks].v, bh, acc[jt]);
      }
    {  // diag[row] = DIAG_C * sum(k^2)
      float s2 = ssq;
      s2 += __shfl_xor(s2, 16);
      s2 += __shfl_xor(s2, 32);
      if (jw == 0 && q == 0) diag[mw * 16 + cl] = DIAG_C * s2;
    }
    __syncthreads();
    // phase 2: kp = RATIO*(exp(dd - diag - m) + eps); store bf16 planes [j][n]
#pragma unroll
    for (int jt = 0; jt < 8; ++jt) {
      int j = jw * 128 + jt * 16 + cl;
      float kv[4];
#pragma unroll
      for (int r = 0; r < 4; ++r) {
        int row = mw * 16 + q * 4 + r;
        float e_ = RATIO_C * (__expf(acc[jt][r] - diag[row] - m) + KEPS_C);
        kv[r] = e_;
        ksacc[jt] += e_;
      }
#pragma unroll
      for (int p = 0; p < 2; ++p) {
        ushort h0 = bf16h(kv[2 * p]), h1 = bf16h(kv[2 * p + 1]);
        ushort l0 = bf16h(kv[2 * p] - bf16f(h0));
        ushort l1 = bf16h(kv[2 * p + 1] - bf16f(h1));
        int ui = j * KPS + mw * 16 + q * 4 + 2 * p;
        *(uint*)&kphi[ui] = (uint)h0 | ((uint)h1 << 16);
        *(uint*)&kplo[ui] = (uint)l0 | ((uint)l1 << 16);
      }
    }
    __syncthreads();
    // phase 3: ctx[j][e] += kp^T * v  (K = 32 = one k-step)
    v8s bhv[4], blv[4];
#pragma unroll
    for (int et = 0; et < 4; ++et) {
      int e = et * 16 + cl;
      bhv[et] = *(const v8s*)&vthi[e * KPS + q * 8];
      blv[et] = *(const v8s*)&vtlo[e * KPS + q * 8];
    }
#pragma unroll
    for (int jj = 0; jj < 4; ++jj) {
      int jrow = (w * 4 + jj) * 16 + cl;
      v8s ah2 = *(const v8s*)&kphi[jrow * KPS + q * 8];
      v8s al2 = *(const v8s*)&kplo[jrow * KPS + q * 8];
#pragma unroll
      for (int et = 0; et < 4; ++et) {
        ctxacc[jj][et] = MFMA(ah2, bhv[et], ctxacc[jj][et]);
        ctxacc[jj][et] = MFMA(ah2, blv[et], ctxacc[jj][et]);
        ctxacc[jj][et] = MFMA(al2, bhv[et], ctxacc[jj][et]);
      }
    }
  }
  // ksum: lane sums rows of its quad; combine quads via shuffle
#pragma unroll
  for (int jt = 0; jt < 8; ++jt) {
    float s = ksacc[jt];
    s += __shfl_xor(s, 16);
    s += __shfl_xor(s, 32);
    if (q == 0) atomicAdd(&ksum[head * NFEAT + jw * 128 + jt * 16 + cl], s);
  }
#pragma unroll
  for (int jj = 0; jj < 4; ++jj)
#pragma unroll
    for (int et = 0; et < 4; ++et)
#pragma unroll
      for (int r = 0; r < 4; ++r) {
        int j = (w * 4 + jj) * 16 + q * 4 + r;
        int e = et * 16 + cl;
        atomicAdd(&ctx[((size_t)head * NFEAT + j) * DHEAD + e],
                  ctxacc[jj][et][r]);
      }
}

// ---------------------------------------------------------------------------
// ctxprep: ctx fp32 [h][j][e] -> ctxT bf16 hi/lo planes [h][e][j]
// ---------------------------------------------------------------------------
__global__ void ctxprep_kernel(const float* __restrict__ ctx,
                               ushort* __restrict__ ctxThi,
                               ushort* __restrict__ ctxTlo) {
  __shared__ float tile[64 * 65];
  const int head = blockIdx.x >> 2, jb = blockIdx.x & 3, t = threadIdx.x;
#pragma unroll
  for (int i = 0; i < 16; ++i) {
    int idx = t + i * 256;
    int jj = idx >> 6, e = idx & 63;
    tile[jj * 65 + e] = ctx[((size_t)head * NFEAT + jb * 64 + jj) * DHEAD + e];
  }
  __syncthreads();
#pragma unroll
  for (int i = 0; i < 16; ++i) {
    int idx = t + i * 256;
    int e = idx >> 6, jj = idx & 63;
    float x = tile[jj * 65 + e];
    ushort h = bf16h(x);
    size_t o = ((size_t)head * DHEAD + e) * NFEAT + jb * 64 + jj;
    ctxThi[o] = h;
    ctxTlo[o] = bf16h(x - bf16f(h));
  }
}

// ---------------------------------------------------------------------------
// qout: dd_q -> rowmax -> qp -> LDS; d_inv; out = (qp . ctx) * d_inv
// 1024 blocks, XCD-swizzled so each head's ctxT stays in one XCD L2.
// ---------------------------------------------------------------------------
#define QPS 264
__global__ __launch_bounds__(256, 3) void qout_kernel(
    const float* __restrict__ qq, const ushort* __restrict__ Phi,
    const ushort* __restrict__ Plo, const float* __restrict__ ksum,
    const ushort* __restrict__ ctxThi, const ushort* __restrict__ ctxTlo,
    float* __restrict__ out) {
  __shared__ __align__(16) ushort qphi[32 * QPS];  // 16.5 KB
  __shared__ __align__(16) ushort qplo[32 * QPS];
  __shared__ float diag[32], mpart[2][32], dpart[2][32], dinv[32];
  const int t = threadIdx.x, lane = t & 63, w = t >> 6;
  const int cl = lane & 15, q = lane >> 4;
  const int mw = w & 1, jw = w >> 1;
  const int xcd = blockIdx.x & 7, bi = blockIdx.x >> 3;
  const int head = ((bi >> 5) << 3) | xcd, slab = bi & 31;
  float ksl[8];
#pragma unroll
  for (int jt = 0; jt < 8; ++jt)
    ksl[jt] = ksum[head * NFEAT + jw * 128 + jt * 16 + cl];
  const float* abase =
      qq + ((size_t)(head * NSEQ + slab * 128 + mw * 16 + cl)) * DHEAD + q * 8;
  float4 pa0 = *(const float4*)(abase);
  float4 pa1 = *(const float4*)(abase + 4);
  float4 pa2 = *(const float4*)(abase + 32);
  float4 pa3 = *(const float4*)(abase + 36);

  for (int c = 0; c < 4; ++c) {
    const int row0 = slab * 128 + c * 32;
    float af[2][8] = {{pa0.x, pa0.y, pa0.z, pa0.w, pa1.x, pa1.y, pa1.z, pa1.w},
                      {pa2.x, pa2.y, pa2.z, pa2.w, pa3.x, pa3.y, pa3.z, pa3.w}};
    Frag8 ah[2], al[2];
    float ssq = 0.f;
#pragma unroll
    for (int ks = 0; ks < 2; ++ks)
#pragma unroll
      for (int i = 0; i < 8; ++i) {
        float x = af[ks][i];
        ssq = fmaf(x, x, ssq);
        ushort h = bf16h(x);
        ah[ks].u[i] = h;
        al[ks].u[i] = bf16h(x - bf16f(h));
      }
    if (c < 3) {
      const float* nx = abase + (size_t)(c + 1) * 32 * DHEAD;
      pa0 = *(const float4*)(nx);
      pa1 = *(const float4*)(nx + 4);
      pa2 = *(const float4*)(nx + 32);
      pa3 = *(const float4*)(nx + 36);
    }
    __syncthreads();  // qp/dinv free (prev phase3 done)
    v4f acc[8];
#pragma unroll
    for (int jt = 0; jt < 8; ++jt) acc[jt] = (v4f){0.f, 0.f, 0.f, 0.f};
#pragma unroll
    for (int ks = 0; ks < 2; ++ks)
#pragma unroll
      for (int jt = 0; jt < 8; ++jt) {
        int j = jw * 128 + jt * 16 + cl;
        v8s bh = *(const v8s*)(Phi + j * 64 + ks * 32 + q * 8);
        v8s bl = *(const v8s*)(Plo + j * 64 + ks * 32 + q * 8);
        acc[jt] = MFMA(ah[ks].v, bh, acc[jt]);
        acc[jt] = MFMA(ah[ks].v, bl, acc[jt]);
        acc[jt] = MFMA(al[ks].v, bh, acc[jt]);
      }
    {
      float s2 = ssq;
      s2 += __shfl_xor(s2, 16);
      s2 += __shfl_xor(s2, 32);
      if (jw == 0 && q == 0) diag[mw * 16 + cl] = DIAG_C * s2;
    }
    // per-row max over this wave's j-half
#pragma unroll
    for (int r = 0; r < 4; ++r) {
      float mr = acc[0][r];
#pragma unroll
      for (int jt = 1; jt < 8; ++jt) mr = fmaxf(mr, acc[jt][r]);
      mr = fmaxf(mr, __shfl_xor(mr, 1));
      mr = fmaxf(mr, __shfl_xor(mr, 2));
      mr = fmaxf(mr, __shfl_xor(mr, 4));
      mr = fmaxf(mr, __shfl_xor(mr, 8));
      if (cl == 0) mpart[jw][mw * 16 + q * 4 + r] = mr;
    }
    __syncthreads();
    // exp, qp store, d_inv dot
#pragma unroll
    for (int r = 0; r < 4; ++r) {
      int row = mw * 16 + q * 4 + r;
      float mm = fmaxf(mpart[0][row], mpart[1][row]) + diag[row];
      float ds = 0.f;
#pragma unroll
      for (int jt = 0; jt < 8; ++jt) {
        float qv = RATIO_C * (__expf(acc[jt][r] - mm) + KEPS_C);
        ds = fmaf(qv, ksl[jt], ds);
        int j = jw * 128 + jt * 16 + cl;
        ushort h = bf16h(qv);
        qphi[row * QPS + j] = h;
        qplo[row * QPS + j] = bf16h(qv - bf16f(h));
      }
      ds += __shfl_xor(ds, 1);
      ds += __shfl_xor(ds, 2);
      ds += __shfl_xor(ds, 4);
      ds += __shfl_xor(ds, 8);
      if (cl == 0) dpart[jw][row] = ds;
    }
    __syncthreads();
    if (t < 32) dinv[t] = 1.0f / (dpart[0][t] + dpart[1][t]);
    __syncthreads();
    // phase 3: out = qp . ctxT, K = 256 (8 k-steps)
    const int mw3 = w & 1, ew = w >> 1;
    v4f oacc[2];
    oacc[0] = (v4f){0.f, 0.f, 0.f, 0.f};
    oacc[1] = (v4f){0.f, 0.f, 0.f, 0.f};
#pragma unroll
    for (int ks8 = 0; ks8 < 8; ++ks8) {
      int nrow = mw3 * 16 + cl;
      v8s ahq = *(const v8s*)&qphi[nrow * QPS + ks8 * 32 + q * 8];
      v8s alq = *(const v8s*)&qplo[nrow * QPS + ks8 * 32 + q * 8];
#pragma unroll
      for (int eti = 0; eti < 2; ++eti) {
        int e = (ew * 2 + eti) * 16 + cl;
        size_t co = ((size_t)head * DHEAD + e) * NFEAT + ks8 * 32 + q * 8;
        v8s bh = *(const v8s*)(ctxThi + co);
        v8s bl = *(const v8s*)(ctxTlo + co);
        oacc[eti] = MFMA(ahq, bh, oacc[eti]);
        oacc[eti] = MFMA(ahq, bl, oacc[eti]);
        oacc[eti] = MFMA(alq, bh, oacc[eti]);
      }
    }
#pragma unroll
    for (int eti = 0; eti < 2; ++eti)
#pragma unroll
      for (int r = 0; r < 4; ++r) {
        int row = mw3 * 16 + q * 4 + r;
        int e = (ew * 2 + eti) * 16 + cl;
        out[((size_t)(head * NSEQ + row0 + row)) * DHEAD + e] =
            oacc[eti][r] * dinv[row];
      }
  }
}

extern "C" void kernel_launch(void* const* d_in, const int* in_sizes, int n_in,
                              void* d_out, int out_size, void* d_ws, size_t ws_size,
                              hipStream_t stream) {
  (void)in_sizes; (void)n_in; (void)out_size; (void)ws_size;
  const float* q = (const float*)d_in[0];
  const float* k = (const float*)d_in[1];
  const float* v = (const float*)d_in[2];
  const float* proj = (const float*)d_in[3];
  float* out = (float*)d_out;
  unsigned char* ws = (unsigned char*)d_ws;
  unsigned* kmax_u = (unsigned*)ws;                    // @0
  float* ksum = (float*)(ws + 256);                    // 32 KB
  float* ctx = (float*)(ws + 33024);                   // 2 MB
  ushort* Phi = (ushort*)(ws + 2130176);               // 32 KB
  ushort* Plo = (ushort*)(ws + 2162944);               // 32 KB
  ushort* ctxThi = (ushort*)(ws + 2195712);            // 1 MB
  ushort* ctxTlo = (ushort*)(ws + 3244288);            // 1 MB -> end 4292864
  hipMemsetAsync(d_ws, 0, 2130176, stream);  // kmax_u + ksum + ctx
  hipLaunchKernelGGL(prep_kernel, dim3(64), dim3(256), 0, stream, proj, Phi, Plo);
  hipLaunchKernelGGL(kmax_kernel, dim3(1024), dim3(256), 0, stream, k, Phi, Plo,
                     kmax_u);
  hipLaunchKernelGGL(kctx_kernel, dim3(1024), dim3(256), 0, stream, k, v, Phi,
                     Plo, kmax_u, ksum, ctx);
  hipLaunchKernelGGL(ctxprep_kernel, dim3(128), dim3(256), 0, stream, ctx,
                     ctxThi, ctxTlo);
  hipLaunchKernelGGL(qout_kernel, dim3(1024), dim3(256), 0, stream, q, Phi, Plo,
                     ksum, ctxThi, ctxTlo, out);
}

// Round 4
// 429.673 us; speedup vs baseline: 1.4652x; 1.4652x over previous
//
#include <hip/hip_runtime.h>

#define NFEAT 256
#define DHEAD 64
#define NSEQ  4096
#define NHEADS 32

constexpr float NORM_C  = 0.35355339059327373f;  // 64^-0.25
constexpr float RATIO_C = 0.0625f;               // 256^-0.5
constexpr float DIAG_C  = 0.0625f;               // 0.5 * 64^-0.5
constexpr float KEPS_C  = 1e-4f;

using v8s = __attribute__((ext_vector_type(8))) short;
using v4f = __attribute__((ext_vector_type(4))) float;
union Frag8 { v8s v; ushort u[8]; };

__device__ __forceinline__ ushort bf16h(float x) {
  unsigned u = __float_as_uint(x);
  return (ushort)((u + 0x7FFFu + ((u >> 16) & 1)) >> 16);
}
__device__ __forceinline__ float bf16f(ushort h) {
  return __uint_as_float(((unsigned)h) << 16);
}
__device__ __forceinline__ unsigned enc_f(float f) {
  unsigned u = __float_as_uint(f);
  return (u & 0x80000000u) ? ~u : (u | 0x80000000u);
}
__device__ __forceinline__ float dec_f(unsigned e) {
  return (e & 0x80000000u) ? __uint_as_float(e ^ 0x80000000u) : __uint_as_float(~e);
}

#define MFMA(a, b, c) __builtin_amdgcn_mfma_f32_16x16x32_bf16((a), (b), (c), 0, 0, 0)

// split P (with NORM folded) into bf16 hi/lo planes, layout [j][d]
__global__ void prep_kernel(const float* __restrict__ proj,
                            ushort* __restrict__ Phi, ushort* __restrict__ Plo) {
  int i = blockIdx.x * 256 + threadIdx.x;
  if (i < NFEAT * DHEAD) {
    float x = NORM_C * proj[i];
    ushort h = bf16h(x);
    Phi[i] = h;
    Plo[i] = bf16h(x - bf16f(h));
  }
}

// ---------------------------------------------------------------------------
// kmax: global max of dd_k via MFMA. 512 blocks: head = bid>>4, slab = bid&15
// (256 rows, 8 chunks of 32). A prefetched one chunk ahead.
// ---------------------------------------------------------------------------
__global__ __launch_bounds__(256, 3) void kmax_kernel(
    const float* __restrict__ kk, const ushort* __restrict__ Phi,
    const ushort* __restrict__ Plo, unsigned* __restrict__ kmax_u) {
  __shared__ float wred[4];
  const int t = threadIdx.x, lane = t & 63, w = t >> 6;
  const int cl = lane & 15, q = lane >> 4;
  const int mw = w & 1, jw = w >> 1;
  const int head = blockIdx.x >> 4, slab = blockIdx.x & 15;
  const float* abase =
      kk + ((size_t)(head * NSEQ + slab * 256 + mw * 16 + cl)) * DHEAD + q * 8;
  float4 pa0 = *(const float4*)(abase);
  float4 pa1 = *(const float4*)(abase + 4);
  float4 pa2 = *(const float4*)(abase + 32);
  float4 pa3 = *(const float4*)(abase + 36);
  float mx = -3.0e38f;
  for (int c = 0; c < 8; ++c) {
    float af[2][8] = {{pa0.x, pa0.y, pa0.z, pa0.w, pa1.x, pa1.y, pa1.z, pa1.w},
                      {pa2.x, pa2.y, pa2.z, pa2.w, pa3.x, pa3.y, pa3.z, pa3.w}};
    Frag8 ah[2], al[2];
#pragma unroll
    for (int ks = 0; ks < 2; ++ks)
#pragma unroll
      for (int i = 0; i < 8; ++i) {
        ushort h = bf16h(af[ks][i]);
        ah[ks].u[i] = h;
        al[ks].u[i] = bf16h(af[ks][i] - bf16f(h));
      }
    if (c < 7) {  // prefetch next chunk
      const float* nx = abase + (size_t)(c + 1) * 32 * DHEAD;
      pa0 = *(const float4*)(nx);
      pa1 = *(const float4*)(nx + 4);
      pa2 = *(const float4*)(nx + 32);
      pa3 = *(const float4*)(nx + 36);
    }
    v4f acc[8];
#pragma unroll
    for (int jt = 0; jt < 8; ++jt) acc[jt] = (v4f){0.f, 0.f, 0.f, 0.f};
#pragma unroll
    for (int ks = 0; ks < 2; ++ks)
#pragma unroll
      for (int jt = 0; jt < 8; ++jt) {
        int j = jw * 128 + jt * 16 + cl;
        v8s bh = *(const v8s*)(Phi + j * 64 + ks * 32 + q * 8);
        v8s bl = *(const v8s*)(Plo + j * 64 + ks * 32 + q * 8);
        acc[jt] = MFMA(ah[ks].v, bh, acc[jt]);
        acc[jt] = MFMA(ah[ks].v, bl, acc[jt]);
        acc[jt] = MFMA(al[ks].v, bh, acc[jt]);
      }
#pragma unroll
    for (int jt = 0; jt < 8; ++jt)
#pragma unroll
      for (int r = 0; r < 4; ++r) mx = fmaxf(mx, acc[jt][r]);
  }
  for (int s = 1; s < 64; s <<= 1) mx = fmaxf(mx, __shfl_xor(mx, s));
  if (lane == 0) wred[w] = mx;
  __syncthreads();
  if (t == 0)
    atomicMax(kmax_u,
              enc_f(fmaxf(fmaxf(wred[0], wred[1]), fmaxf(wred[2], wred[3]))));
}

// ---------------------------------------------------------------------------
// kctx: dd_k -> kp (exp) -> LDS -> ctx += kp^T * v, ksum += kp.
// 512 blocks (round-2 grid, no swizzle). A/V prefetched one chunk ahead.
// ---------------------------------------------------------------------------
#define KPS 40
__global__ __launch_bounds__(256, 2) void kctx_kernel(
    const float* __restrict__ kk, const float* __restrict__ vv,
    const ushort* __restrict__ Phi, const ushort* __restrict__ Plo,
    const unsigned* __restrict__ kmax_u, float* __restrict__ ksum,
    float* __restrict__ ctx) {
  __shared__ __align__(16) ushort kphi[NFEAT * KPS];  // 20 KB  [j][n]
  __shared__ __align__(16) ushort kplo[NFEAT * KPS];  // 20 KB
  __shared__ __align__(16) ushort vthi[DHEAD * KPS];  // 5 KB   [e][n]
  __shared__ __align__(16) ushort vtlo[DHEAD * KPS];  // 5 KB
  __shared__ float diag[32];
  const int t = threadIdx.x, lane = t & 63, w = t >> 6;
  const int cl = lane & 15, q = lane >> 4;
  const int mw = w & 1, jw = w >> 1;
  const int head = blockIdx.x >> 4, slab = blockIdx.x & 15;
  const float m = dec_f(*kmax_u);
  float ksacc[8] = {0.f, 0.f, 0.f, 0.f, 0.f, 0.f, 0.f, 0.f};
  v4f ctxacc[4][4];
#pragma unroll
  for (int jj = 0; jj < 4; ++jj)
#pragma unroll
    for (int et = 0; et < 4; ++et) ctxacc[jj][et] = (v4f){0.f, 0.f, 0.f, 0.f};

  const float* abase =
      kk + ((size_t)(head * NSEQ + slab * 256 + mw * 16 + cl)) * DHEAD + q * 8;
  const int np = t >> 4, e0 = (t & 15) * 4;
  const float* vbase =
      vv + ((size_t)(head * NSEQ + slab * 256 + np * 2)) * DHEAD + e0;
  float4 pa0 = *(const float4*)(abase);
  float4 pa1 = *(const float4*)(abase + 4);
  float4 pa2 = *(const float4*)(abase + 32);
  float4 pa3 = *(const float4*)(abase + 36);
  float4 pv0 = *(const float4*)(vbase);
  float4 pv1 = *(const float4*)(vbase + DHEAD);

  for (int c = 0; c < 8; ++c) {
    __syncthreads();  // kp/vt free (prev phase3 done)
    // stage v^T (bf16 hi/lo), layout [e][n], from prefetched regs
    {
      float fa[4] = {pv0.x, pv0.y, pv0.z, pv0.w};
      float fb[4] = {pv1.x, pv1.y, pv1.z, pv1.w};
#pragma unroll
      for (int cc = 0; cc < 4; ++cc) {
        int e = e0 + cc;
        ushort h0 = bf16h(fa[cc]), h1 = bf16h(fb[cc]);
        ushort l0 = bf16h(fa[cc] - bf16f(h0)), l1 = bf16h(fb[cc] - bf16f(h1));
        *(uint*)&vthi[e * KPS + np * 2] = (uint)h0 | ((uint)h1 << 16);
        *(uint*)&vtlo[e * KPS + np * 2] = (uint)l0 | ((uint)l1 << 16);
      }
    }
    // A split from prefetched regs
    float af[2][8] = {{pa0.x, pa0.y, pa0.z, pa0.w, pa1.x, pa1.y, pa1.z, pa1.w},
                      {pa2.x, pa2.y, pa2.z, pa2.w, pa3.x, pa3.y, pa3.z, pa3.w}};
    Frag8 ah[2], al[2];
    float ssq = 0.f;
#pragma unroll
    for (int ks = 0; ks < 2; ++ks)
#pragma unroll
      for (int i = 0; i < 8; ++i) {
        float x = af[ks][i];
        ssq = fmaf(x, x, ssq);
        ushort h = bf16h(x);
        ah[ks].u[i] = h;
        al[ks].u[i] = bf16h(x - bf16f(h));
      }
    if (c < 7) {  // prefetch next chunk
      const float* nx = abase + (size_t)(c + 1) * 32 * DHEAD;
      pa0 = *(const float4*)(nx);
      pa1 = *(const float4*)(nx + 4);
      pa2 = *(const float4*)(nx + 32);
      pa3 = *(const float4*)(nx + 36);
      const float* nv = vbase + (size_t)(c + 1) * 32 * DHEAD;
      pv0 = *(const float4*)(nv);
      pv1 = *(const float4*)(nv + DHEAD);
    }
    // phase 1: dd_k tile via MFMA
    v4f acc[8];
#pragma unroll
    for (int jt = 0; jt < 8; ++jt) acc[jt] = (v4f){0.f, 0.f, 0.f, 0.f};
#pragma unroll
    for (int ks = 0; ks < 2; ++ks)
#pragma unroll
      for (int jt = 0; jt < 8; ++jt) {
        int j = jw * 128 + jt * 16 + cl;
        v8s bh = *(const v8s*)(Phi + j * 64 + ks * 32 + q * 8);
        v8s bl = *(const v8s*)(Plo + j * 64 + ks * 32 + q * 8);
        acc[jt] = MFMA(ah[ks].v, bh, acc[jt]);
        acc[jt] = MFMA(ah[ks].v, bl, acc[jt]);
        acc[jt] = MFMA(al[ks].v, bh, acc[jt]);
      }
    {  // diag[row] = DIAG_C * sum(k^2)
      float s2 = ssq;
      s2 += __shfl_xor(s2, 16);
      s2 += __shfl_xor(s2, 32);
      if (jw == 0 && q == 0) diag[mw * 16 + cl] = DIAG_C * s2;
    }
    __syncthreads();
    // phase 2: kp = RATIO*(exp(dd - diag - m) + eps); store bf16 planes [j][n]
#pragma unroll
    for (int jt = 0; jt < 8; ++jt) {
      int j = jw * 128 + jt * 16 + cl;
      float kv[4];
#pragma unroll
      for (int r = 0; r < 4; ++r) {
        int row = mw * 16 + q * 4 + r;
        float e_ = RATIO_C * (__expf(acc[jt][r] - diag[row] - m) + KEPS_C);
        kv[r] = e_;
        ksacc[jt] += e_;
      }
#pragma unroll
      for (int p = 0; p < 2; ++p) {
        ushort h0 = bf16h(kv[2 * p]), h1 = bf16h(kv[2 * p + 1]);
        ushort l0 = bf16h(kv[2 * p] - bf16f(h0));
        ushort l1 = bf16h(kv[2 * p + 1] - bf16f(h1));
        int ui = j * KPS + mw * 16 + q * 4 + 2 * p;
        *(uint*)&kphi[ui] = (uint)h0 | ((uint)h1 << 16);
        *(uint*)&kplo[ui] = (uint)l0 | ((uint)l1 << 16);
      }
    }
    __syncthreads();
    // phase 3: ctx[j][e] += kp^T * v  (K = 32 = one k-step)
    v8s bhv[4], blv[4];
#pragma unroll
    for (int et = 0; et < 4; ++et) {
      int e = et * 16 + cl;
      bhv[et] = *(const v8s*)&vthi[e * KPS + q * 8];
      blv[et] = *(const v8s*)&vtlo[e * KPS + q * 8];
    }
#pragma unroll
    for (int jj = 0; jj < 4; ++jj) {
      int jrow = (w * 4 + jj) * 16 + cl;
      v8s ah2 = *(const v8s*)&kphi[jrow * KPS + q * 8];
      v8s al2 = *(const v8s*)&kplo[jrow * KPS + q * 8];
#pragma unroll
      for (int et = 0; et < 4; ++et) {
        ctxacc[jj][et] = MFMA(ah2, bhv[et], ctxacc[jj][et]);
        ctxacc[jj][et] = MFMA(ah2, blv[et], ctxacc[jj][et]);
        ctxacc[jj][et] = MFMA(al2, bhv[et], ctxacc[jj][et]);
      }
    }
  }
  // ksum: lane sums rows of its quad; combine quads via shuffle
#pragma unroll
  for (int jt = 0; jt < 8; ++jt) {
    float s = ksacc[jt];
    s += __shfl_xor(s, 16);
    s += __shfl_xor(s, 32);
    if (q == 0) atomicAdd(&ksum[head * NFEAT + jw * 128 + jt * 16 + cl], s);
  }
#pragma unroll
  for (int jj = 0; jj < 4; ++jj)
#pragma unroll
    for (int et = 0; et < 4; ++et)
#pragma unroll
      for (int r = 0; r < 4; ++r) {
        int j = (w * 4 + jj) * 16 + q * 4 + r;
        int e = et * 16 + cl;
        atomicAdd(&ctx[((size_t)head * NFEAT + j) * DHEAD + e],
                  ctxacc[jj][et][r]);
      }
}

// ---------------------------------------------------------------------------
// ctxprep: ctx fp32 [h][j][e] -> ctxT bf16 hi/lo planes [h][e][j]
// ---------------------------------------------------------------------------
__global__ void ctxprep_kernel(const float* __restrict__ ctx,
                               ushort* __restrict__ ctxThi,
                               ushort* __restrict__ ctxTlo) {
  __shared__ float tile[64 * 65];
  const int head = blockIdx.x >> 2, jb = blockIdx.x & 3, t = threadIdx.x;
#pragma unroll
  for (int i = 0; i < 16; ++i) {
    int idx = t + i * 256;
    int jj = idx >> 6, e = idx & 63;
    tile[jj * 65 + e] = ctx[((size_t)head * NFEAT + jb * 64 + jj) * DHEAD + e];
  }
  __syncthreads();
#pragma unroll
  for (int i = 0; i < 16; ++i) {
    int idx = t + i * 256;
    int e = idx >> 6, jj = idx & 63;
    float x = tile[jj * 65 + e];
    ushort h = bf16h(x);
    size_t o = ((size_t)head * DHEAD + e) * NFEAT + jb * 64 + jj;
    ctxThi[o] = h;
    ctxTlo[o] = bf16h(x - bf16f(h));
  }
}

// ---------------------------------------------------------------------------
// qout: dd_q -> rowmax -> qp -> LDS; d_inv; out = (qp . ctx) * d_inv.
// 512 blocks. ctxT B-fragments loaded ONCE into registers (64 VGPRs/wave),
// reused across all 8 chunks: phase 3 has zero global traffic. Epilogue
// staged in LDS and stored fully coalesced (8 KB contiguous per chunk).
// ---------------------------------------------------------------------------
#define QPS 264
#define OS 68
__global__ __launch_bounds__(256, 3) void qout_kernel(
    const float* __restrict__ qq, const ushort* __restrict__ Phi,
    const ushort* __restrict__ Plo, const float* __restrict__ ksum,
    const ushort* __restrict__ ctxThi, const ushort* __restrict__ ctxTlo,
    float* __restrict__ out) {
  __shared__ __align__(16) ushort qphi[32 * QPS];  // 16.5 KB
  __shared__ __align__(16) ushort qplo[32 * QPS];
  __shared__ __align__(16) float souts[32 * OS];   // 8.5 KB
  __shared__ float diag[32], mpart[2][32], dpart[2][32], dinv[32];
  const int t = threadIdx.x, lane = t & 63, w = t >> 6;
  const int cl = lane & 15, q = lane >> 4;
  const int mw = w & 1, jw = w >> 1;
  const int head = blockIdx.x >> 4, slab = blockIdx.x & 15;
  float ksl[8];
#pragma unroll
  for (int jt = 0; jt < 8; ++jt)
    ksl[jt] = ksum[head * NFEAT + jw * 128 + jt * 16 + cl];
  // B-fragments resident: wave w owns e-tile w (e = w*16+cl), all 8 k-steps
  v8s bhr[8], blr[8];
  {
    const ushort* bh0 = ctxThi + ((size_t)head * DHEAD + w * 16 + cl) * NFEAT + q * 8;
    const ushort* bl0 = ctxTlo + ((size_t)head * DHEAD + w * 16 + cl) * NFEAT + q * 8;
#pragma unroll
    for (int ks8 = 0; ks8 < 8; ++ks8) {
      bhr[ks8] = *(const v8s*)(bh0 + ks8 * 32);
      blr[ks8] = *(const v8s*)(bl0 + ks8 * 32);
    }
  }
  const float* abase =
      qq + ((size_t)(head * NSEQ + slab * 256 + mw * 16 + cl)) * DHEAD + q * 8;
  float4 pa0 = *(const float4*)(abase);
  float4 pa1 = *(const float4*)(abase + 4);
  float4 pa2 = *(const float4*)(abase + 32);
  float4 pa3 = *(const float4*)(abase + 36);

  for (int c = 0; c < 8; ++c) {
    const int row0 = slab * 256 + c * 32;
    float af[2][8] = {{pa0.x, pa0.y, pa0.z, pa0.w, pa1.x, pa1.y, pa1.z, pa1.w},
                      {pa2.x, pa2.y, pa2.z, pa2.w, pa3.x, pa3.y, pa3.z, pa3.w}};
    Frag8 ah[2], al[2];
    float ssq = 0.f;
#pragma unroll
    for (int ks = 0; ks < 2; ++ks)
#pragma unroll
      for (int i = 0; i < 8; ++i) {
        float x = af[ks][i];
        ssq = fmaf(x, x, ssq);
        ushort h = bf16h(x);
        ah[ks].u[i] = h;
        al[ks].u[i] = bf16h(x - bf16f(h));
      }
    if (c < 7) {
      const float* nx = abase + (size_t)(c + 1) * 32 * DHEAD;
      pa0 = *(const float4*)(nx);
      pa1 = *(const float4*)(nx + 4);
      pa2 = *(const float4*)(nx + 32);
      pa3 = *(const float4*)(nx + 36);
    }
    __syncthreads();  // qp free (prev chunk fully consumed)
    // phase 1: dd_q via MFMA (P frags from global; L2-resident 128 KB)
    v4f acc[8];
#pragma unroll
    for (int jt = 0; jt < 8; ++jt) acc[jt] = (v4f){0.f, 0.f, 0.f, 0.f};
#pragma unroll
    for (int ks = 0; ks < 2; ++ks)
#pragma unroll
      for (int jt = 0; jt < 8; ++jt) {
        int j = jw * 128 + jt * 16 + cl;
        v8s bh = *(const v8s*)(Phi + j * 64 + ks * 32 + q * 8);
        v8s bl = *(const v8s*)(Plo + j * 64 + ks * 32 + q * 8);
        acc[jt] = MFMA(ah[ks].v, bh, acc[jt]);
        acc[jt] = MFMA(ah[ks].v, bl, acc[jt]);
        acc[jt] = MFMA(al[ks].v, bh, acc[jt]);
      }
    {
      float s2 = ssq;
      s2 += __shfl_xor(s2, 16);
      s2 += __shfl_xor(s2, 32);
      if (jw == 0 && q == 0) diag[mw * 16 + cl] = DIAG_C * s2;
    }
    // per-row max over this wave's j-half
#pragma unroll
    for (int r = 0; r < 4; ++r) {
      float mr = acc[0][r];
#pragma unroll
      for (int jt = 1; jt < 8; ++jt) mr = fmaxf(mr, acc[jt][r]);
      mr = fmaxf(mr, __shfl_xor(mr, 1));
      mr = fmaxf(mr, __shfl_xor(mr, 2));
      mr = fmaxf(mr, __shfl_xor(mr, 4));
      mr = fmaxf(mr, __shfl_xor(mr, 8));
      if (cl == 0) mpart[jw][mw * 16 + q * 4 + r] = mr;
    }
    __syncthreads();
    // exp, qp store, d_inv dot
#pragma unroll
    for (int r = 0; r < 4; ++r) {
      int row = mw * 16 + q * 4 + r;
      float mm = fmaxf(mpart[0][row], mpart[1][row]) + diag[row];
      float ds = 0.f;
#pragma unroll
      for (int jt = 0; jt < 8; ++jt) {
        float qv = RATIO_C * (__expf(acc[jt][r] - mm) + KEPS_C);
        ds = fmaf(qv, ksl[jt], ds);
        int j = jw * 128 + jt * 16 + cl;
        ushort h = bf16h(qv);
        qphi[row * QPS + j] = h;
        qplo[row * QPS + j] = bf16h(qv - bf16f(h));
      }
      ds += __shfl_xor(ds, 1);
      ds += __shfl_xor(ds, 2);
      ds += __shfl_xor(ds, 4);
      ds += __shfl_xor(ds, 8);
      if (cl == 0) dpart[jw][row] = ds;
    }
    __syncthreads();
    if (t < 32) dinv[t] = 1.0f / (dpart[0][t] + dpart[1][t]);
    __syncthreads();
    // phase 3: out-tile = qp . ctxT (B resident in regs); wave w -> e-tile w
    v4f oacc[2];
    oacc[0] = (v4f){0.f, 0.f, 0.f, 0.f};
    oacc[1] = (v4f){0.f, 0.f, 0.f, 0.f};
#pragma unroll
    for (int ks8 = 0; ks8 < 8; ++ks8) {
#pragma unroll
      for (int mt = 0; mt < 2; ++mt) {
        v8s ahq = *(const v8s*)&qphi[(mt * 16 + cl) * QPS + ks8 * 32 + q * 8];
        v8s alq = *(const v8s*)&qplo[(mt * 16 + cl) * QPS + ks8 * 32 + q * 8];
        oacc[mt] = MFMA(ahq, bhr[ks8], oacc[mt]);
        oacc[mt] = MFMA(ahq, blr[ks8], oacc[mt]);
        oacc[mt] = MFMA(alq, bhr[ks8], oacc[mt]);
      }
    }
    // stage (x d_inv) into LDS, then fully-coalesced store of 32x64 tile
#pragma unroll
    for (int mt = 0; mt < 2; ++mt)
#pragma unroll
      for (int r = 0; r < 4; ++r) {
        int row = mt * 16 + q * 4 + r;
        souts[row * OS + w * 16 + cl] = oacc[mt][r] * dinv[row];
      }
    __syncthreads();
    {
      const int row = t >> 3, eo = (t & 7) * 8;
      float4 r0 = *(const float4*)&souts[row * OS + eo];
      float4 r1 = *(const float4*)&souts[row * OS + eo + 4];
      float* ob = out + ((size_t)(head * NSEQ + row0 + row)) * DHEAD + eo;
      *(float4*)ob = r0;
      *(float4*)(ob + 4) = r1;
    }
  }
}

extern "C" void kernel_launch(void* const* d_in, const int* in_sizes, int n_in,
                              void* d_out, int out_size, void* d_ws, size_t ws_size,
                              hipStream_t stream) {
  (void)in_sizes; (void)n_in; (void)out_size; (void)ws_size;
  const float* q = (const float*)d_in[0];
  const float* k = (const float*)d_in[1];
  const float* v = (const float*)d_in[2];
  const float* proj = (const float*)d_in[3];
  float* out = (float*)d_out;
  unsigned char* ws = (unsigned char*)d_ws;
  unsigned* kmax_u = (unsigned*)ws;                    // @0
  float* ksum = (float*)(ws + 256);                    // 32 KB
  float* ctx = (float*)(ws + 33024);                   // 2 MB
  ushort* Phi = (ushort*)(ws + 2130176);               // 32 KB
  ushort* Plo = (ushort*)(ws + 2162944);               // 32 KB
  ushort* ctxThi = (ushort*)(ws + 2195712);            // 1 MB
  ushort* ctxTlo = (ushort*)(ws + 3244288);            // 1 MB -> end 4292864
  hipMemsetAsync(d_ws, 0, 2130176, stream);  // kmax_u + ksum + ctx
  hipLaunchKernelGGL(prep_kernel, dim3(64), dim3(256), 0, stream, proj, Phi, Plo);
  hipLaunchKernelGGL(kmax_kernel, dim3(512), dim3(256), 0, stream, k, Phi, Plo,
                     kmax_u);
  hipLaunchKernelGGL(kctx_kernel, dim3(512), dim3(256), 0, stream, k, v, Phi,
                     Plo, kmax_u, ksum, ctx);
  hipLaunchKernelGGL(ctxprep_kernel, dim3(128), dim3(256), 0, stream, ctx,
                     ctxThi, ctxTlo);
  hipLaunchKernelGGL(qout_kernel, dim3(512), dim3(256), 0, stream, q, Phi, Plo,
                     ksum, ctxThi, ctxTlo, out);
}

// Round 5
// 261.442 us; speedup vs baseline: 2.4081x; 1.6435x over previous
//
#include <hip/hip_runtime.h>

#define NFEAT 256
#define DHEAD 64
#define NSEQ  4096
#define NHEADS 32

constexpr float NORM_C  = 0.35355339059327373f;  // 64^-0.25
constexpr float RATIO_C = 0.0625f;               // 256^-0.5
constexpr float DIAG_C  = 0.0625f;               // 0.5 * 64^-0.5
constexpr float KEPS_C  = 1e-4f;

using v8s = __attribute__((ext_vector_type(8))) short;
using v4f = __attribute__((ext_vector_type(4))) float;
union Frag8 { v8s v; ushort u[8]; };

__device__ __forceinline__ ushort bf16h(float x) {
  unsigned u = __float_as_uint(x);
  return (ushort)((u + 0x7FFFu + ((u >> 16) & 1)) >> 16);
}
__device__ __forceinline__ float bf16f(ushort h) {
  return __uint_as_float(((unsigned)h) << 16);
}
__device__ __forceinline__ unsigned enc_f(float f) {
  unsigned u = __float_as_uint(f);
  return (u & 0x80000000u) ? ~u : (u | 0x80000000u);
}
__device__ __forceinline__ float dec_f(unsigned e) {
  return (e & 0x80000000u) ? __uint_as_float(e ^ 0x80000000u) : __uint_as_float(~e);
}

#define MFMA(a, b, c) __builtin_amdgcn_mfma_f32_16x16x32_bf16((a), (b), (c), 0, 0, 0)

// P (NORM folded) -> bf16 hi/lo planes in FRAGMENT-MAJOR layout:
//   P2[(d>>3)*256*8 + j*8 + (d&7)]
// so a lane's v8s fragment (j, dslice=q*8+ks*32) is 16 contiguous bytes.
__global__ void prep_kernel(const float* __restrict__ proj,
                            ushort* __restrict__ P2hi, ushort* __restrict__ P2lo) {
  int i = blockIdx.x * 256 + threadIdx.x;
  if (i < NFEAT * DHEAD) {
    int j = i >> 6, d = i & 63;
    float x = NORM_C * proj[i];
    ushort h = bf16h(x);
    int off = ((d >> 3) * NFEAT + j) * 8 + (d & 7);
    P2hi[off] = h;
    P2lo[off] = bf16h(x - bf16f(h));
  }
}

// ---------------------------------------------------------------------------
// kmax: global max of dd_k via MFMA. 512 blocks x 256 thr; P in LDS.
// ---------------------------------------------------------------------------
__global__ __launch_bounds__(256, 2) void kmax_kernel(
    const float* __restrict__ kk, const ushort* __restrict__ P2hi,
    const ushort* __restrict__ P2lo, unsigned* __restrict__ kmax_u) {
  __shared__ __align__(16) ushort PhiL[NFEAT * DHEAD];  // 32 KB
  __shared__ __align__(16) ushort PloL[NFEAT * DHEAD];  // 32 KB
  __shared__ float wred[4];
  const int t = threadIdx.x, lane = t & 63, w = t >> 6;
  const int cl = lane & 15, q = lane >> 4;
  const int mw = w & 1, jw = w >> 1;
  const int head = blockIdx.x >> 4, slab = blockIdx.x & 15;
  for (int i = t; i < 4096; i += 256) {
    ((float4*)PhiL)[i] = ((const float4*)P2hi)[i];
    ((float4*)PloL)[i] = ((const float4*)P2lo)[i];
  }
  const float* abase =
      kk + ((size_t)(head * NSEQ + slab * 256 + mw * 16 + cl)) * DHEAD + q * 8;
  float4 pa0 = *(const float4*)(abase);
  float4 pa1 = *(const float4*)(abase + 4);
  float4 pa2 = *(const float4*)(abase + 32);
  float4 pa3 = *(const float4*)(abase + 36);
  __syncthreads();
  float mx = -3.0e38f;
  for (int c = 0; c < 8; ++c) {
    float af[2][8] = {{pa0.x, pa0.y, pa0.z, pa0.w, pa1.x, pa1.y, pa1.z, pa1.w},
                      {pa2.x, pa2.y, pa2.z, pa2.w, pa3.x, pa3.y, pa3.z, pa3.w}};
    Frag8 ah[2], al[2];
#pragma unroll
    for (int ks = 0; ks < 2; ++ks)
#pragma unroll
      for (int i = 0; i < 8; ++i) {
        ushort h = bf16h(af[ks][i]);
        ah[ks].u[i] = h;
        al[ks].u[i] = bf16h(af[ks][i] - bf16f(h));
      }
    if (c < 7) {
      const float* nx = abase + (size_t)(c + 1) * 32 * DHEAD;
      pa0 = *(const float4*)(nx);
      pa1 = *(const float4*)(nx + 4);
      pa2 = *(const float4*)(nx + 32);
      pa3 = *(const float4*)(nx + 36);
    }
    v4f acc[8];
#pragma unroll
    for (int jt = 0; jt < 8; ++jt) acc[jt] = (v4f){0.f, 0.f, 0.f, 0.f};
#pragma unroll
    for (int ks = 0; ks < 2; ++ks)
#pragma unroll
      for (int jt = 0; jt < 8; ++jt) {
        int pidx = ((ks * 4 + q) * NFEAT + jw * 128 + jt * 16 + cl) * 8;
        v8s bh = *(const v8s*)&PhiL[pidx];
        v8s bl = *(const v8s*)&PloL[pidx];
        acc[jt] = MFMA(ah[ks].v, bh, acc[jt]);
        acc[jt] = MFMA(ah[ks].v, bl, acc[jt]);
        acc[jt] = MFMA(al[ks].v, bh, acc[jt]);
      }
#pragma unroll
    for (int jt = 0; jt < 8; ++jt)
#pragma unroll
      for (int r = 0; r < 4; ++r) mx = fmaxf(mx, acc[jt][r]);
  }
  for (int s = 1; s < 64; s <<= 1) mx = fmaxf(mx, __shfl_xor(mx, s));
  if (lane == 0) wred[w] = mx;
  __syncthreads();
  if (t == 0)
    atomicMax(kmax_u,
              enc_f(fmaxf(fmaxf(wred[0], wred[1]), fmaxf(wred[2], wred[3]))));
}

// ---------------------------------------------------------------------------
// kctx: dd_k -> kp (exp) -> LDS -> ctx += kp^T * v, ksum += kp.
// 256 blocks x 512 thr (1 block/CU, 8 waves). P in LDS. 16 chunks of 32 rows.
// Phase-1 waves: (mw = w&1 row-half, jq = w>>1 j-quarter).
// Phase-3 waves: (eh = w&1 e-half, jq3 = w>>1 j-quarter).
// ---------------------------------------------------------------------------
#define KPS 40
#define VTS 40
__global__ __launch_bounds__(512, 2) void kctx_kernel(
    const float* __restrict__ kk, const float* __restrict__ vv,
    const ushort* __restrict__ P2hi, const ushort* __restrict__ P2lo,
    const unsigned* __restrict__ kmax_u, float* __restrict__ ksum,
    float* __restrict__ ctx) {
  __shared__ __align__(16) ushort PhiL[NFEAT * DHEAD];  // 32 KB
  __shared__ __align__(16) ushort PloL[NFEAT * DHEAD];  // 32 KB
  __shared__ __align__(16) ushort kphi[NFEAT * KPS];    // 20 KB [j][n]
  __shared__ __align__(16) ushort kplo[NFEAT * KPS];    // 20 KB
  __shared__ __align__(16) ushort vthi[DHEAD * VTS];    // 5 KB  [e][n]
  __shared__ __align__(16) ushort vtlo[DHEAD * VTS];    // 5 KB
  __shared__ float diag[32];
  const int t = threadIdx.x, lane = t & 63, w = t >> 6;
  const int cl = lane & 15, q = lane >> 4;
  const int mw = w & 1, jq = w >> 1;
  const int head = blockIdx.x >> 3, slab = blockIdx.x & 7;
  const float m = dec_f(*kmax_u);
  for (int i = t; i < 4096; i += 512) {
    ((float4*)PhiL)[i] = ((const float4*)P2hi)[i];
    ((float4*)PloL)[i] = ((const float4*)P2lo)[i];
  }
  float ksacc[4] = {0.f, 0.f, 0.f, 0.f};
  v4f ctxacc[4][2];
#pragma unroll
  for (int jj = 0; jj < 4; ++jj)
#pragma unroll
    for (int et = 0; et < 2; ++et) ctxacc[jj][et] = (v4f){0.f, 0.f, 0.f, 0.f};

  const float* abase =
      kk + ((size_t)(head * NSEQ + slab * 512 + mw * 16 + cl)) * DHEAD + q * 8;
  const int vrow = t >> 4, ve0 = (t & 15) * 4;
  const float* vbase =
      vv + ((size_t)(head * NSEQ + slab * 512 + vrow)) * DHEAD + ve0;
  float4 pa0 = *(const float4*)(abase);
  float4 pa1 = *(const float4*)(abase + 4);
  float4 pa2 = *(const float4*)(abase + 32);
  float4 pa3 = *(const float4*)(abase + 36);
  float4 pv0 = *(const float4*)(vbase);

  for (int c = 0; c < 16; ++c) {
    __syncthreads();  // prev phase3 done with kp/vt (iter0: P staged)
    {  // stage v^T bf16 hi/lo [e][n]
      float fv[4] = {pv0.x, pv0.y, pv0.z, pv0.w};
#pragma unroll
      for (int cc = 0; cc < 4; ++cc) {
        int e = ve0 + cc;
        ushort h = bf16h(fv[cc]);
        vthi[e * VTS + vrow] = h;
        vtlo[e * VTS + vrow] = bf16h(fv[cc] - bf16f(h));
      }
    }
    float af[2][8] = {{pa0.x, pa0.y, pa0.z, pa0.w, pa1.x, pa1.y, pa1.z, pa1.w},
                      {pa2.x, pa2.y, pa2.z, pa2.w, pa3.x, pa3.y, pa3.z, pa3.w}};
    Frag8 ah[2], al[2];
    float ssq = 0.f;
#pragma unroll
    for (int ks = 0; ks < 2; ++ks)
#pragma unroll
      for (int i = 0; i < 8; ++i) {
        float x = af[ks][i];
        ssq = fmaf(x, x, ssq);
        ushort h = bf16h(x);
        ah[ks].u[i] = h;
        al[ks].u[i] = bf16h(x - bf16f(h));
      }
    if (c < 15) {  // prefetch next chunk
      const float* nx = abase + (size_t)(c + 1) * 32 * DHEAD;
      pa0 = *(const float4*)(nx);
      pa1 = *(const float4*)(nx + 4);
      pa2 = *(const float4*)(nx + 32);
      pa3 = *(const float4*)(nx + 36);
      pv0 = *(const float4*)(vbase + (size_t)(c + 1) * 32 * DHEAD);
    }
    // phase 1: dd_k (this wave: rows mw*16+*, j-quarter jq)
    v4f acc[4];
#pragma unroll
    for (int jt = 0; jt < 4; ++jt) acc[jt] = (v4f){0.f, 0.f, 0.f, 0.f};
#pragma unroll
    for (int ks = 0; ks < 2; ++ks)
#pragma unroll
      for (int jt = 0; jt < 4; ++jt) {
        int pidx = ((ks * 4 + q) * NFEAT + jq * 64 + jt * 16 + cl) * 8;
        v8s bh = *(const v8s*)&PhiL[pidx];
        v8s bl = *(const v8s*)&PloL[pidx];
        acc[jt] = MFMA(ah[ks].v, bh, acc[jt]);
        acc[jt] = MFMA(ah[ks].v, bl, acc[jt]);
        acc[jt] = MFMA(al[ks].v, bh, acc[jt]);
      }
    {
      float s2 = ssq;
      s2 += __shfl_xor(s2, 16);
      s2 += __shfl_xor(s2, 32);
      if (jq == 0 && q == 0) diag[mw * 16 + cl] = DIAG_C * s2;
    }
    __syncthreads();
    // phase 2: kp = RATIO*(exp(dd - diag - m) + eps) -> bf16 planes [j][n]
#pragma unroll
    for (int jt = 0; jt < 4; ++jt) {
      int j = jq * 64 + jt * 16 + cl;
      float kv[4];
#pragma unroll
      for (int r = 0; r < 4; ++r) {
        int row = mw * 16 + q * 4 + r;
        float e_ = RATIO_C * (__expf(acc[jt][r] - diag[row] - m) + KEPS_C);
        kv[r] = e_;
        ksacc[jt] += e_;
      }
#pragma unroll
      for (int p = 0; p < 2; ++p) {
        ushort h0 = bf16h(kv[2 * p]), h1 = bf16h(kv[2 * p + 1]);
        ushort l0 = bf16h(kv[2 * p] - bf16f(h0));
        ushort l1 = bf16h(kv[2 * p + 1] - bf16f(h1));
        int ui = j * KPS + mw * 16 + q * 4 + 2 * p;
        *(uint*)&kphi[ui] = (uint)h0 | ((uint)h1 << 16);
        *(uint*)&kplo[ui] = (uint)l0 | ((uint)l1 << 16);
      }
    }
    __syncthreads();
    // phase 3: ctx[j][e] += kp^T * v (wave: e-half eh, j-quarter jq3)
    const int eh = w & 1, jq3 = w >> 1;
    v8s bhv[2], blv[2];
#pragma unroll
    for (int et = 0; et < 2; ++et) {
      int e = (eh * 2 + et) * 16 + cl;
      bhv[et] = *(const v8s*)&vthi[e * VTS + q * 8];
      blv[et] = *(const v8s*)&vtlo[e * VTS + q * 8];
    }
#pragma unroll
    for (int jj = 0; jj < 4; ++jj) {
      int jrow = jq3 * 64 + jj * 16 + cl;
      v8s ah2 = *(const v8s*)&kphi[jrow * KPS + q * 8];
      v8s al2 = *(const v8s*)&kplo[jrow * KPS + q * 8];
#pragma unroll
      for (int et = 0; et < 2; ++et) {
        ctxacc[jj][et] = MFMA(ah2, bhv[et], ctxacc[jj][et]);
        ctxacc[jj][et] = MFMA(ah2, blv[et], ctxacc[jj][et]);
        ctxacc[jj][et] = MFMA(al2, bhv[et], ctxacc[jj][et]);
      }
    }
  }
#pragma unroll
  for (int jt = 0; jt < 4; ++jt) {
    float s = ksacc[jt];
    s += __shfl_xor(s, 16);
    s += __shfl_xor(s, 32);
    if (q == 0) atomicAdd(&ksum[head * NFEAT + jq * 64 + jt * 16 + cl], s);
  }
  {
    const int eh = w & 1, jq3 = w >> 1;
#pragma unroll
    for (int jj = 0; jj < 4; ++jj)
#pragma unroll
      for (int et = 0; et < 2; ++et)
#pragma unroll
        for (int r = 0; r < 4; ++r) {
          int j = jq3 * 64 + jj * 16 + q * 4 + r;
          int e = (eh * 2 + et) * 16 + cl;
          atomicAdd(&ctx[((size_t)head * NFEAT + j) * DHEAD + e],
                    ctxacc[jj][et][r]);
        }
  }
}

// ---------------------------------------------------------------------------
// ctxprep: ctx fp32 [h][j][e] -> ctxT bf16 hi/lo planes [h][e][j]
// ---------------------------------------------------------------------------
__global__ void ctxprep_kernel(const float* __restrict__ ctx,
                               ushort* __restrict__ ctxThi,
                               ushort* __restrict__ ctxTlo) {
  __shared__ float tile[64 * 65];
  const int head = blockIdx.x >> 2, jb = blockIdx.x & 3, t = threadIdx.x;
#pragma unroll
  for (int i = 0; i < 16; ++i) {
    int idx = t + i * 256;
    int jj = idx >> 6, e = idx & 63;
    tile[jj * 65 + e] = ctx[((size_t)head * NFEAT + jb * 64 + jj) * DHEAD + e];
  }
  __syncthreads();
#pragma unroll
  for (int i = 0; i < 16; ++i) {
    int idx = t + i * 256;
    int e = idx >> 6, jj = idx & 63;
    float x = tile[jj * 65 + e];
    ushort h = bf16h(x);
    size_t o = ((size_t)head * DHEAD + e) * NFEAT + jb * 64 + jj;
    ctxThi[o] = h;
    ctxTlo[o] = bf16h(x - bf16f(h));
  }
}

// ---------------------------------------------------------------------------
// qout: dd_q -> rowmax -> qp -> LDS; d_inv; out = (qp . ctxT) * d_inv.
// 256 blocks x 512 thr (1 block/CU). P in LDS; ctxT B-frags in registers
// (wave (mw3,et3) owns a 16x16 (m,e)-tile with full K=256). 16 chunks.
// ---------------------------------------------------------------------------
#define QPS 264
#define OS 68
__global__ __launch_bounds__(512, 2) void qout_kernel(
    const float* __restrict__ qq, const ushort* __restrict__ P2hi,
    const ushort* __restrict__ P2lo, const float* __restrict__ ksum,
    const ushort* __restrict__ ctxThi, const ushort* __restrict__ ctxTlo,
    float* __restrict__ out) {
  __shared__ __align__(16) ushort PhiL[NFEAT * DHEAD];  // 32 KB
  __shared__ __align__(16) ushort PloL[NFEAT * DHEAD];  // 32 KB
  __shared__ __align__(16) ushort qphi[32 * QPS];       // 16.5 KB [n][j]
  __shared__ __align__(16) ushort qplo[32 * QPS];
  __shared__ __align__(16) float souts[32 * OS];        // 8.5 KB
  __shared__ float diag[32];
  __shared__ float mpart[4][32], dpart[4][32];
  const int t = threadIdx.x, lane = t & 63, w = t >> 6;
  const int cl = lane & 15, q = lane >> 4;
  const int mw = w & 1, jq = w >> 1;     // phase-1 mapping
  const int mw3 = w & 1, et3 = w >> 1;   // phase-3 mapping
  const int head = blockIdx.x >> 3, slab = blockIdx.x & 7;
  for (int i = t; i < 4096; i += 512) {
    ((float4*)PhiL)[i] = ((const float4*)P2hi)[i];
    ((float4*)PloL)[i] = ((const float4*)P2lo)[i];
  }
  float ksl[4];
#pragma unroll
  for (int jt = 0; jt < 4; ++jt)
    ksl[jt] = ksum[head * NFEAT + jq * 64 + jt * 16 + cl];
  // register-resident ctxT B-fragments (loaded once)
  v8s bhr[8], blr[8];
  {
    const size_t bo = ((size_t)head * DHEAD + et3 * 16 + cl) * NFEAT + q * 8;
#pragma unroll
    for (int ks8 = 0; ks8 < 8; ++ks8) {
      bhr[ks8] = *(const v8s*)(ctxThi + bo + ks8 * 32);
      blr[ks8] = *(const v8s*)(ctxTlo + bo + ks8 * 32);
    }
  }
  const float* abase =
      qq + ((size_t)(head * NSEQ + slab * 512 + mw * 16 + cl)) * DHEAD + q * 8;
  float4 pa0 = *(const float4*)(abase);
  float4 pa1 = *(const float4*)(abase + 4);
  float4 pa2 = *(const float4*)(abase + 32);
  float4 pa3 = *(const float4*)(abase + 36);
  __syncthreads();  // P staged

  for (int c = 0; c < 16; ++c) {
    const int row0 = slab * 512 + c * 32;
    float af[2][8] = {{pa0.x, pa0.y, pa0.z, pa0.w, pa1.x, pa1.y, pa1.z, pa1.w},
                      {pa2.x, pa2.y, pa2.z, pa2.w, pa3.x, pa3.y, pa3.z, pa3.w}};
    Frag8 ah[2], al[2];
    float ssq = 0.f;
#pragma unroll
    for (int ks = 0; ks < 2; ++ks)
#pragma unroll
      for (int i = 0; i < 8; ++i) {
        float x = af[ks][i];
        ssq = fmaf(x, x, ssq);
        ushort h = bf16h(x);
        ah[ks].u[i] = h;
        al[ks].u[i] = bf16h(x - bf16f(h));
      }
    if (c < 15) {
      const float* nx = abase + (size_t)(c + 1) * 32 * DHEAD;
      pa0 = *(const float4*)(nx);
      pa1 = *(const float4*)(nx + 4);
      pa2 = *(const float4*)(nx + 32);
      pa3 = *(const float4*)(nx + 36);
    }
    // phase 1: dd_q (rows mw*16+*, j-quarter jq)
    v4f acc[4];
#pragma unroll
    for (int jt = 0; jt < 4; ++jt) acc[jt] = (v4f){0.f, 0.f, 0.f, 0.f};
#pragma unroll
    for (int ks = 0; ks < 2; ++ks)
#pragma unroll
      for (int jt = 0; jt < 4; ++jt) {
        int pidx = ((ks * 4 + q) * NFEAT + jq * 64 + jt * 16 + cl) * 8;
        v8s bh = *(const v8s*)&PhiL[pidx];
        v8s bl = *(const v8s*)&PloL[pidx];
        acc[jt] = MFMA(ah[ks].v, bh, acc[jt]);
        acc[jt] = MFMA(ah[ks].v, bl, acc[jt]);
        acc[jt] = MFMA(al[ks].v, bh, acc[jt]);
      }
    {
      float s2 = ssq;
      s2 += __shfl_xor(s2, 16);
      s2 += __shfl_xor(s2, 32);
      if (jq == 0 && q == 0) diag[mw * 16 + cl] = DIAG_C * s2;
    }
    // per-row max over this wave's j-quarter
#pragma unroll
    for (int r = 0; r < 4; ++r) {
      float mr = acc[0][r];
#pragma unroll
      for (int jt = 1; jt < 4; ++jt) mr = fmaxf(mr, acc[jt][r]);
      mr = fmaxf(mr, __shfl_xor(mr, 1));
      mr = fmaxf(mr, __shfl_xor(mr, 2));
      mr = fmaxf(mr, __shfl_xor(mr, 4));
      mr = fmaxf(mr, __shfl_xor(mr, 8));
      if (cl == 0) mpart[jq][mw * 16 + q * 4 + r] = mr;
    }
    __syncthreads();
    // phase 2: exp, qp store, d-partials
#pragma unroll
    for (int r = 0; r < 4; ++r) {
      int row = mw * 16 + q * 4 + r;
      float mm = fmaxf(fmaxf(mpart[0][row], mpart[1][row]),
                       fmaxf(mpart[2][row], mpart[3][row])) + diag[row];
      float ds = 0.f;
#pragma unroll
      for (int jt = 0; jt < 4; ++jt) {
        float qv = RATIO_C * (__expf(acc[jt][r] - mm) + KEPS_C);
        ds = fmaf(qv, ksl[jt], ds);
        int j = jq * 64 + jt * 16 + cl;
        ushort h = bf16h(qv);
        qphi[row * QPS + j] = h;
        qplo[row * QPS + j] = bf16h(qv - bf16f(h));
      }
      ds += __shfl_xor(ds, 1);
      ds += __shfl_xor(ds, 2);
      ds += __shfl_xor(ds, 4);
      ds += __shfl_xor(ds, 8);
      if (cl == 0) dpart[jq][row] = ds;
    }
    __syncthreads();
    // phase 3: (m,e)-tile GEMM, K=256, B in registers
    v4f oacc = (v4f){0.f, 0.f, 0.f, 0.f};
#pragma unroll
    for (int ks8 = 0; ks8 < 8; ++ks8) {
      v8s ahq = *(const v8s*)&qphi[(mw3 * 16 + cl) * QPS + ks8 * 32 + q * 8];
      v8s alq = *(const v8s*)&qplo[(mw3 * 16 + cl) * QPS + ks8 * 32 + q * 8];
      oacc = MFMA(ahq, bhr[ks8], oacc);
      oacc = MFMA(ahq, blr[ks8], oacc);
      oacc = MFMA(alq, bhr[ks8], oacc);
    }
#pragma unroll
    for (int r = 0; r < 4; ++r) {
      int row = mw3 * 16 + q * 4 + r;
      float di = 1.0f / (dpart[0][row] + dpart[1][row] + dpart[2][row] +
                         dpart[3][row]);
      souts[row * OS + et3 * 16 + cl] = oacc[r] * di;
    }
    __syncthreads();
    {  // coalesced 32x64 tile store
      const int row = t >> 4, eo = (t & 15) * 4;
      float4 rr = *(const float4*)&souts[row * OS + eo];
      *(float4*)(out + ((size_t)(head * NSEQ + row0 + row)) * DHEAD + eo) = rr;
    }
    __syncthreads();  // souts/qp consumed before next chunk overwrites
  }
}

extern "C" void kernel_launch(void* const* d_in, const int* in_sizes, int n_in,
                              void* d_out, int out_size, void* d_ws, size_t ws_size,
                              hipStream_t stream) {
  (void)in_sizes; (void)n_in; (void)out_size; (void)ws_size;
  const float* q = (const float*)d_in[0];
  const float* k = (const float*)d_in[1];
  const float* v = (const float*)d_in[2];
  const float* proj = (const float*)d_in[3];
  float* out = (float*)d_out;
  unsigned char* ws = (unsigned char*)d_ws;
  unsigned* kmax_u = (unsigned*)ws;                    // @0
  float* ksum = (float*)(ws + 256);                    // 32 KB
  float* ctx = (float*)(ws + 33024);                   // 2 MB
  ushort* P2hi = (ushort*)(ws + 2130176);              // 32 KB
  ushort* P2lo = (ushort*)(ws + 2162944);              // 32 KB
  ushort* ctxThi = (ushort*)(ws + 2195712);            // 1 MB
  ushort* ctxTlo = (ushort*)(ws + 3244288);            // 1 MB -> end 4292864
  hipMemsetAsync(d_ws, 0, 2130176, stream);  // kmax_u + ksum + ctx
  hipLaunchKernelGGL(prep_kernel, dim3(64), dim3(256), 0, stream, proj, P2hi, P2lo);
  hipLaunchKernelGGL(kmax_kernel, dim3(512), dim3(256), 0, stream, k, P2hi, P2lo,
                     kmax_u);
  hipLaunchKernelGGL(kctx_kernel, dim3(256), dim3(512), 0, stream, k, v, P2hi,
                     P2lo, kmax_u, ksum, ctx);
  hipLaunchKernelGGL(ctxprep_kernel, dim3(128), dim3(256), 0, stream, ctx,
                     ctxThi, ctxTlo);
  hipLaunchKernelGGL(qout_kernel, dim3(256), dim3(512), 0, stream, q, P2hi,
                     P2lo, ksum, ctxThi, ctxTlo, out);
}